// Round 1
// baseline (46.103 us; speedup 1.0000x reference)
//
#include <hip/hip_runtime.h>

// BbRelProjection: per-sample closed-form QP projections.
//   QP1: y0 = clip(p0, lx, ux)
//   QP2: 2-point isotonic (pool to mean if out of order) then clip to [lx,ux]
//   QP3: 3-var chain: t from 3 stationary cases, clip t to [ly,uy],
//        ya/yb = clip(pa/pb, ly, t)
// Memory-bound: 16 f32/sample total traffic; vectorize everything as float4
// by processing 2 samples per thread (12 f32 y_pred, 8 f32 constr, 12 f32 out).

__device__ __forceinline__ void project6(const float* __restrict__ p,
                                         const float* __restrict__ c,
                                         float* __restrict__ o) {
    const float lx = c[0], ux = c[1], ly = c[2], uy = c[3];
    // QP1: simple clamp
    o[0] = fminf(fmaxf(p[0], lx), ux);
    // QP2: 2-point isotonic regression then clip
    const float p1 = p[1], p2 = p[2];
    const float avg = 0.5f * (p1 + p2);
    const bool swap = p1 > p2;
    const float q1 = swap ? avg : p1;
    const float q2 = swap ? avg : p2;
    o[1] = fminf(fmaxf(q1, lx), ux);
    o[2] = fminf(fmaxf(q2, lx), ux);
    // QP3
    const float pa = p[3], pb = p[4], pc = p[5];
    const float m  = fmaxf(pa, pb);
    const float mn = fminf(pa, pb);
    const float t_all = (pa + pb + pc) / 3.0f;
    const float t_one = 0.5f * (pc + m);
    float t = (pc >= m) ? pc : ((t_all < mn) ? t_all : t_one);
    t = fminf(fmaxf(t, ly), uy);
    o[3] = fminf(fmaxf(pa, ly), t);   // clip(pa, ly, t): min(max(x,lo),hi) order matches jnp.clip
    o[4] = fminf(fmaxf(pb, ly), t);
    o[5] = t;
}

__global__ void __launch_bounds__(256)
bbrel_proj_pair_kernel(const float4* __restrict__ yp,   // y_pred as float4 (3 per pair)
                       const float4* __restrict__ cp,   // constr as float4 (2 per pair)
                       float4* __restrict__ out,        // out as float4 (3 per pair)
                       int npairs) {
    const int t = blockIdx.x * blockDim.x + threadIdx.x;
    if (t >= npairs) return;

    const float4 v0 = yp[3 * t + 0];
    const float4 v1 = yp[3 * t + 1];
    const float4 v2 = yp[3 * t + 2];
    const float4 c0 = cp[2 * t + 0];
    const float4 c1 = cp[2 * t + 1];

    float p[12] = {v0.x, v0.y, v0.z, v0.w,
                   v1.x, v1.y, v1.z, v1.w,
                   v2.x, v2.y, v2.z, v2.w};
    float c[8]  = {c0.x, c0.y, c0.z, c0.w,
                   c1.x, c1.y, c1.z, c1.w};
    float o[12];

    project6(p,     c,     o);      // sample 2t
    project6(p + 6, c + 4, o + 6);  // sample 2t+1

    const float4 r0 = {o[0], o[1],  o[2],  o[3]};
    const float4 r1 = {o[4], o[5],  o[6],  o[7]};
    const float4 r2 = {o[8], o[9], o[10], o[11]};
    out[3 * t + 0] = r0;
    out[3 * t + 1] = r1;
    out[3 * t + 2] = r2;
}

// Scalar fallback for a possible odd-tail sample (not hit at BATCH=4194304).
__global__ void bbrel_proj_tail_kernel(const float* __restrict__ yp,
                                       const float* __restrict__ cp,
                                       float* __restrict__ out,
                                       int sample_idx) {
    if (threadIdx.x != 0 || blockIdx.x != 0) return;
    float p[6], c[4], o[6];
    for (int k = 0; k < 6; ++k) p[k] = yp[6 * sample_idx + k];
    for (int k = 0; k < 4; ++k) c[k] = cp[4 * sample_idx + k];
    project6(p, c, o);
    for (int k = 0; k < 6; ++k) out[6 * sample_idx + k] = o[k];
}

extern "C" void kernel_launch(void* const* d_in, const int* in_sizes, int n_in,
                              void* d_out, int out_size, void* d_ws, size_t ws_size,
                              hipStream_t stream) {
    const float* y_pred = (const float*)d_in[0];   // (N, 6) fp32
    const float* constr = (const float*)d_in[1];   // (N, 4) fp32
    float* out = (float*)d_out;                    // (N, 6) fp32

    const int n = in_sizes[0] / 6;
    const int npairs = n / 2;

    if (npairs > 0) {
        const int block = 256;
        const int grid = (npairs + block - 1) / block;
        bbrel_proj_pair_kernel<<<grid, block, 0, stream>>>(
            (const float4*)y_pred, (const float4*)constr, (float4*)out, npairs);
    }
    if (n & 1) {
        bbrel_proj_tail_kernel<<<1, 64, 0, stream>>>(y_pred, constr, out, n - 1);
    }
}